// Round 13
// baseline (1087.498 us; speedup 1.0000x reference)
//
#include <hip/hip_runtime.h>
#include <hip/hip_fp16.h>

#define NN 100000
#define NE 1600000
#define FIN 64
#define HID 128
#define NL 4
#define NG 512
#define FFN 300
#define BN_EPS 1e-5f
#define LDH 136   // padded LDS stride in halves
#define NB 512    // CSR buckets
#define NPB 196   // nodes per bucket
#define CURPAD 16
#define NCH 8     // feature chunks; chunk slab = NN*16*2B = 3.2 MB < 4 MB L2
#define CH 16

static inline size_t alignup(size_t x) { return (x + 255) & ~(size_t)255; }

struct half8 { __half2 h[4]; };   // 16 B

typedef _Float16 f16;
typedef __attribute__((ext_vector_type(4))) _Float16 f16x4;
typedef __attribute__((ext_vector_type(8))) _Float16 f16x8;
typedef __attribute__((ext_vector_type(4))) float f32x4;

// ======================= CSR build (bucketed, dense writes) =======================
__global__ __launch_bounds__(1024) void k_bcount(const int* __restrict__ col,
                                                 int* __restrict__ bcnt) {
    __shared__ int h[NB];
    int t = threadIdx.x;
    if (t < NB) h[t] = 0;
    __syncthreads();
    for (int e = blockIdx.x * 1024 + t; e < NE; e += 256 * 1024)
        atomicAdd(&h[col[e] / NPB], 1);
    __syncthreads();
    if (t < NB && h[t] > 0) atomicAdd(&bcnt[t], h[t]);
}

__global__ void k_bscan(const int* __restrict__ bcnt, int* __restrict__ bbase,
                        int* __restrict__ bcur) {
    __shared__ int s[NB];
    int t = threadIdx.x;  // NB threads
    int v = bcnt[t];
    s[t] = v;
    __syncthreads();
    for (int off = 1; off < NB; off <<= 1) {
        int u = (t >= off) ? s[t - off] : 0;
        __syncthreads();
        s[t] += u;
        __syncthreads();
    }
    int excl = s[t] - v;
    bbase[t] = excl;
    bcur[t * CURPAD] = excl;
    if (t == NB - 1) bbase[NB] = s[t];
}

__global__ __launch_bounds__(1024) void k_bscatter2(const int* __restrict__ row,
                                                    const int* __restrict__ col,
                                                    int* __restrict__ bcur,
                                                    int* __restrict__ ebuf) {
    __shared__ int hcnt[NB];
    __shared__ int hbase[NB];
    int t = threadIdx.x;
    int e0 = blockIdx.x * 4096;
    if (t < NB) hcnt[t] = 0;
    __syncthreads();
    #pragma unroll
    for (int k = 0; k < 4; ++k) {
        int e = e0 + k * 1024 + t;
        if (e < NE) atomicAdd(&hcnt[col[e] / NPB], 1);
    }
    __syncthreads();
    if (t < NB) {
        int c = hcnt[t];
        hbase[t] = (c > 0) ? atomicAdd(&bcur[t * CURPAD], c) : 0;
    }
    __syncthreads();
    if (t < NB) hcnt[t] = 0;
    __syncthreads();
    #pragma unroll
    for (int k = 0; k < 4; ++k) {
        int e = e0 + k * 1024 + t;
        if (e < NE) {
            int c = col[e];
            int b = c / NPB;
            int loc = atomicAdd(&hcnt[b], 1);
            ebuf[hbase[b] + loc] = row[e] | ((c - b * NPB) << 17);
        }
    }
}

__global__ __launch_bounds__(256) void k_binfill(const int* __restrict__ ebuf,
                                                 const int* __restrict__ bbase,
                                                 int* __restrict__ offs,
                                                 int* __restrict__ ends,
                                                 float* __restrict__ dinv,
                                                 int* __restrict__ csr_src) {
    __shared__ int cnt[NPB];
    __shared__ int scn[256];
    __shared__ int cur[NPB];
    int b = blockIdx.x, t = threadIdx.x;
    int lo = b * NPB;
    int hi = lo + NPB; if (hi > NN) hi = NN;
    int n = hi - lo;
    if (n <= 0) return;
    int s0 = bbase[b], s1 = bbase[b + 1];
    for (int i = t; i < NPB; i += 256) cnt[i] = 0;
    __syncthreads();
    for (int j = s0 + t; j < s1; j += 256)
        atomicAdd(&cnt[((unsigned)ebuf[j]) >> 17], 1);
    __syncthreads();
    int v = (t < n) ? cnt[t] : 0;
    scn[t] = v;
    __syncthreads();
    for (int off = 1; off < 256; off <<= 1) {
        int u = (t >= off) ? scn[t - off] : 0;
        __syncthreads();
        scn[t] += u;
        __syncthreads();
    }
    if (t < n) {
        int g = s0 + scn[t] - v;
        offs[lo + t] = g;
        ends[lo + t] = g + v;
        dinv[lo + t] = rsqrtf((float)(v + 1));
        cur[t] = g;
    }
    __syncthreads();
    for (int j = s0 + t; j < s1; j += 256) {
        int e = ebuf[j];
        int pos = atomicAdd(&cur[((unsigned)e) >> 17], 1);
        csr_src[pos] = e & 0x1FFFF;
    }
}

// ==== W preconvert: wt[l][c][k] = (f16)Ws[l][k][c]; wte[c][k] = (f16)encW[k][c] ====
__global__ void k_convW(const float* __restrict__ Ws, const float* __restrict__ encW,
                        f16* __restrict__ wt, f16* __restrict__ wte) {
    int tid = blockIdx.x * 256 + threadIdx.x;
    for (int i = tid; i < NL * HID * HID; i += 64 * 256) {
        int l = i >> 14, rem = i & 16383;
        int c = rem >> 7, k = rem & 127;
        wt[i] = (f16)Ws[(l << 14) + k * HID + c];
    }
    for (int i = tid; i < HID * FIN; i += 64 * 256) {
        int c = i >> 6, k = i & 63;
        wte[i] = (f16)encW[k * HID + c];
    }
}

// ======== MFMA encoder: hc[ct][row][16] = (x[N,64] @ encW) + b -> f16 chunked ========
__global__ __launch_bounds__(256) void k_enc_mfma(const float* __restrict__ x,
                                                  const f16* __restrict__ wte,
                                                  const float* __restrict__ b,
                                                  __half* __restrict__ hc) {
    __shared__ f16 sx[64 * 72];
    __shared__ f16 sw[128 * 72];
    int t = threadIdx.x;
    int row0 = blockIdx.x * 64;
    for (int idx = t; idx < 64 * 16; idx += 256) {
        int r = idx >> 4, c4 = (idx & 15) * 4;
        float4 v = {0.0f, 0.0f, 0.0f, 0.0f};
        if (row0 + r < NN) v = *(const float4*)(x + (size_t)(row0 + r) * FIN + c4);
        f16x4 o = {(f16)v.x, (f16)v.y, (f16)v.z, (f16)v.w};
        *(f16x4*)&sx[r * 72 + c4] = o;
    }
    for (int idx = t; idx < 128 * 8; idx += 256) {
        int c = idx >> 3, ch = (idx & 7) * 8;
        *(f16x8*)&sw[c * 72 + ch] = *(const f16x8*)(wte + c * FIN + ch);
    }
    __syncthreads();
    int w = t >> 6, lane = t & 63;
    int lrow = lane & 15, lk = (lane >> 4) * 8;
    f32x4 acc[8];
    #pragma unroll
    for (int ct = 0; ct < 8; ++ct) acc[ct] = (f32x4){0.0f, 0.0f, 0.0f, 0.0f};
    const f16* pa = &sx[(w * 16 + lrow) * 72 + lk];
    #pragma unroll
    for (int ks = 0; ks < 2; ++ks) {
        f16x8 a = *(const f16x8*)(pa + ks * 32);
        #pragma unroll
        for (int ct = 0; ct < 8; ++ct) {
            f16x8 bb = *(const f16x8*)&sw[(ct * 16 + lrow) * 72 + ks * 32 + lk];
            acc[ct] = __builtin_amdgcn_mfma_f32_16x16x32_f16(a, bb, acc[ct], 0, 0, 0);
        }
    }
    float bv[8];
    #pragma unroll
    for (int ct = 0; ct < 8; ++ct) bv[ct] = b[ct * 16 + lrow];
    int rbase = row0 + w * 16 + (lane >> 4) * 4;
    #pragma unroll
    for (int i = 0; i < 4; ++i) {
        int grow = rbase + i;
        if (grow < NN) {
            #pragma unroll
            for (int ct = 0; ct < 8; ++ct)
                hc[((size_t)ct * NN + grow) * CH + lrow] = __float2half(acc[ct][i] + bv[ct]);
        }
    }
}

// ==== MFMA layer GEMM: chunked in, chunked out; hw = dinv[row]*(h @ W) ====
__global__ __launch_bounds__(256) void k_gemm_mfma(const __half* __restrict__ hcin,
                                                   const f16* __restrict__ wt,
                                                   const float* __restrict__ dinv,
                                                   __half* __restrict__ hwc) {
    __shared__ f16 sh[64 * LDH];
    __shared__ f16 sw[128 * LDH];
    int t = threadIdx.x;
    int row0 = blockIdx.x * 64;
    // stage 64 rows x 128 features from chunked layout [c][node][16]
    for (int idx = t; idx < 1024; idx += 256) {
        int cc = idx >> 7;          // chunk
        int l = idx & 127;
        int r = l >> 1, half = l & 1;
        f16x8 v = {0, 0, 0, 0, 0, 0, 0, 0};
        if (row0 + r < NN)
            v = *(const f16x8*)(hcin + ((size_t)cc * NN + row0 + r) * CH + half * 8);
        *(f16x8*)&sh[r * LDH + cc * 16 + half * 8] = v;
    }
    for (int idx = t; idx < 128 * 16; idx += 256) {
        int c = idx >> 4, ch = (idx & 15) * 8;
        *(f16x8*)&sw[c * LDH + ch] = *(const f16x8*)(wt + c * HID + ch);
    }
    __syncthreads();
    int w = t >> 6, lane = t & 63;
    int lrow = lane & 15, lk = (lane >> 4) * 8;
    f32x4 acc[8];
    #pragma unroll
    for (int ct = 0; ct < 8; ++ct) acc[ct] = (f32x4){0.0f, 0.0f, 0.0f, 0.0f};
    const f16* pa = &sh[(w * 16 + lrow) * LDH + lk];
    #pragma unroll
    for (int ks = 0; ks < 4; ++ks) {
        f16x8 a = *(const f16x8*)(pa + ks * 32);
        #pragma unroll
        for (int ct = 0; ct < 8; ++ct) {
            f16x8 b = *(const f16x8*)&sw[(ct * 16 + lrow) * LDH + ks * 32 + lk];
            acc[ct] = __builtin_amdgcn_mfma_f32_16x16x32_f16(a, b, acc[ct], 0, 0, 0);
        }
    }
    int rbase = row0 + w * 16 + (lane >> 4) * 4;
    #pragma unroll
    for (int i = 0; i < 4; ++i) {
        int grow = rbase + i;
        if (grow < NN) {
            float dv = dinv[grow];
            #pragma unroll
            for (int ct = 0; ct < 8; ++ct)
                hwc[((size_t)ct * NN + grow) * CH + lrow] = __float2half(dv * acc[ct][i]);
        }
    }
}

// == XCD-pinned chunked gather: chunk = blockIdx.x & 7 (round-robin -> one XCD
//    per chunk); each XCD's 3.2 MB slab stays L2-resident. Wave per node:
//    8 edge-slots x 8 lanes x half2 (16 features). ==
__global__ __launch_bounds__(256) void k_gather_cp(
    const int* __restrict__ offs, const int* __restrict__ ends,
    const int* __restrict__ csr_src,
    const float* __restrict__ dinv,
    const __half* __restrict__ hwc, const __half* __restrict__ hprevc,
    const float* __restrict__ bias, const float* __restrict__ gamma,
    const float* __restrict__ beta, const float* __restrict__ mean,
    const float* __restrict__ var,
    __half* __restrict__ houtc, int with_res) {
    int bid = blockIdx.x;
    int c = bid & 7;          // chunk == XCD (round-robin dispatch)
    int nb = bid >> 3;
    int w = threadIdx.x >> 6, lane = threadIdx.x & 63;
    int g = lane >> 3, fl = lane & 7;
    const __half* slab = hwc + (size_t)c * NN * CH;
    int f0 = c * CH + fl * 2;
    float2 bi = *(const float2*)(bias + f0);
    float2 mn = *(const float2*)(mean + f0);
    float2 vr = *(const float2*)(var + f0);
    float2 gm = *(const float2*)(gamma + f0);
    float2 bt = *(const float2*)(beta + f0);
    float rs0 = rsqrtf(vr.x + BN_EPS) * gm.x;
    float rs1 = rsqrtf(vr.y + BN_EPS) * gm.y;
    #pragma unroll
    for (int it = 0; it < 4; ++it) {
        int node = nb * 16 + w * 4 + it;
        if (node >= NN) break;  // uniform per wave
        int s = offs[node], e = ends[node];
        float a0 = 0.0f, a1 = 0.0f;
        int j = s + g;
        for (; j + 8 < e; j += 16) {   // 2 loads -> 16 edges in flight per wave
            int s0 = csr_src[j], s1 = csr_src[j + 8];
            float2 v0 = __half22float2(*(const __half2*)(slab + (size_t)s0 * CH + fl * 2));
            float2 v1 = __half22float2(*(const __half2*)(slab + (size_t)s1 * CH + fl * 2));
            a0 += v0.x + v1.x;
            a1 += v0.y + v1.y;
        }
        for (; j < e; j += 8) {
            int s0 = csr_src[j];
            float2 v0 = __half22float2(*(const __half2*)(slab + (size_t)s0 * CH + fl * 2));
            a0 += v0.x;
            a1 += v0.y;
        }
        a0 += __shfl_xor(a0, 8);  a1 += __shfl_xor(a1, 8);
        a0 += __shfl_xor(a0, 16); a1 += __shfl_xor(a1, 16);
        a0 += __shfl_xor(a0, 32); a1 += __shfl_xor(a1, 32);
        if (g == 0) {
            float2 hv = __half22float2(*(const __half2*)(slab + (size_t)node * CH + fl * 2));
            float dc = dinv[node];
            a0 = dc * (a0 + hv.x);
            a1 = dc * (a1 + hv.y);
            float o0 = fmaxf((a0 + bi.x - mn.x) * rs0 + bt.x, 0.0f);
            float o1 = fmaxf((a1 + bi.y - mn.y) * rs1 + bt.y, 0.0f);
            if (with_res) {
                float2 p = __half22float2(
                    *(const __half2*)(hprevc + ((size_t)c * NN + node) * CH + fl * 2));
                o0 += p.x;
                o1 += p.y;
            }
            *(__half2*)(houtc + ((size_t)c * NN + node) * CH + fl * 2) =
                __floats2half2_rn(o0, o1);
        }
    }
}

// ======================= pool (segmented, chunked input) =======================
__device__ __forceinline__ int lower_bound_dev(const int* __restrict__ a, int n, int v) {
    int lo = 0, hi = n;
    while (lo < hi) {
        int m = (lo + hi) >> 1;
        if (a[m] < v) lo = m + 1; else hi = m;
    }
    return lo;
}

__global__ __launch_bounds__(256) void k_pool_seg(const __half* __restrict__ hc,
                                                  const int* __restrict__ batch,
                                                  float* __restrict__ gfeat) {
    __shared__ int range[2];
    __shared__ float s[256];
    int g = blockIdx.x, t = threadIdx.x;
    if (t == 0) {
        range[0] = lower_bound_dev(batch, NN, g);
        range[1] = lower_bound_dev(batch, NN, g + 1);
    }
    __syncthreads();
    int start = range[0], end = range[1];
    int f = t & 127, half = t >> 7;
    int cf = f >> 4, fl = f & 15;
    const __half* slab = hc + (size_t)cf * NN * CH;
    float acc = 0.0f;
    for (int i = start + half; i < end; i += 2)
        acc += __half2float(slab[(size_t)i * CH + fl]);
    s[t] = acc;
    __syncthreads();
    if (t < 128) {
        float sum = s[t] + s[t + 128];
        float cnt = (float)(end - start);
        gfeat[(size_t)g * HID + t] = sum / fmaxf(cnt, 1.0f);
    }
}

// ======================= MLP =======================
__global__ void k_mlp0(const float* __restrict__ gfeat,
                       const float* __restrict__ W, const float* __restrict__ b,
                       float* __restrict__ out) {
    __shared__ float srow[HID];
    int g = blockIdx.x, t = threadIdx.x;  // 128 threads
    if (t < HID) srow[t] = gfeat[(size_t)g * HID + t];
    __syncthreads();
    for (int j = t; j < FFN; j += 128) {
        float acc = b[j];
        for (int k = 0; k < HID; ++k) acc += srow[k] * W[k * FFN + j];
        out[(size_t)g * FFN + j] = fmaxf(acc, 0.0f);
    }
}

__global__ void k_mlp1(const float* __restrict__ in, const float* __restrict__ W,
                       const float* __restrict__ b, float* __restrict__ out) {
    __shared__ float srow[FFN];
    int g = blockIdx.x, t = threadIdx.x;  // 128 threads
    for (int k = t; k < FFN; k += 128) srow[k] = in[(size_t)g * FFN + k];
    __syncthreads();
    for (int j = t; j < FFN; j += 128) {
        float acc = b[j];
        for (int k = 0; k < FFN; ++k) acc += srow[k] * W[k * FFN + j];
        out[(size_t)g * FFN + j] = fmaxf(acc, 0.0f);
    }
}

__global__ void k_mlp2(const float* __restrict__ in, const float* __restrict__ W,
                       const float* __restrict__ b, float* __restrict__ out) {
    int g = blockIdx.x, lane = threadIdx.x;  // 64 threads
    float acc = 0.0f;
    for (int k = lane; k < FFN; k += 64) acc += in[(size_t)g * FFN + k] * W[k];
    for (int off = 32; off > 0; off >>= 1) acc += __shfl_down(acc, off);
    if (lane == 0) out[g] = acc + b[0];
}

extern "C" void kernel_launch(void* const* d_in, const int* in_sizes, int n_in,
                              void* d_out, int out_size, void* d_ws, size_t ws_size,
                              hipStream_t stream) {
    const float* x    = (const float*)d_in[0];
    const int*   ei   = (const int*)d_in[1];    // [2,E]: rows then cols
    const int*   batch= (const int*)d_in[2];
    const float* encW = (const float*)d_in[3];
    const float* encb = (const float*)d_in[4];
    const float* Ws   = (const float*)d_in[5];
    const float* bs   = (const float*)d_in[6];
    const float* gam  = (const float*)d_in[7];
    const float* bet  = (const float*)d_in[8];
    const float* mean = (const float*)d_in[9];
    const float* var  = (const float*)d_in[10];
    const float* W0   = (const float*)d_in[11];
    const float* b0   = (const float*)d_in[12];
    const float* W1   = (const float*)d_in[13];
    const float* b1   = (const float*)d_in[14];
    const float* W2   = (const float*)d_in[15];
    const float* b2   = (const float*)d_in[16];
    float* out = (float*)d_out;

    char* w = (char*)d_ws;
    float*  dinv    = (float*)w;  w += alignup((size_t)NN * 4);
    int*    offs    = (int*)w;    w += alignup((size_t)NN * 4);
    int*    ends    = (int*)w;    w += alignup((size_t)NN * 4);
    int*    csr_src = (int*)w;    w += alignup((size_t)NE * 4);
    int*    bcnt    = (int*)w;    w += alignup((size_t)NB * 4);
    int*    bbase   = (int*)w;    w += alignup((size_t)(NB + 1) * 4);
    int*    bcur    = (int*)w;    w += alignup((size_t)NB * CURPAD * 4);
    int*    ebuf    = (int*)w;    w += alignup((size_t)NE * 4);
    __half* hA      = (__half*)w; w += alignup((size_t)NN * HID * 2);
    __half* hB      = (__half*)w; w += alignup((size_t)NN * HID * 2);
    __half* hw_     = (__half*)w; w += alignup((size_t)NN * HID * 2);
    f16*    wt      = (f16*)w;    w += alignup((size_t)NL * HID * HID * 2);
    f16*    wte     = (f16*)w;    w += alignup((size_t)HID * FIN * 2);
    float*  gfeat   = (float*)w;  w += alignup((size_t)NG * HID * 4);
    float*  m0      = (float*)w;  w += alignup((size_t)NG * FFN * 4);
    float*  m1      = (float*)w;  w += alignup((size_t)NG * FFN * 4);

    const int* row = ei;
    const int* col = ei + NE;

    // ---- CSR build ----
    hipMemsetAsync(bcnt, 0, (size_t)NB * 4, stream);
    k_bcount<<<256, 1024, 0, stream>>>(col, bcnt);
    k_bscan<<<1, NB, 0, stream>>>(bcnt, bbase, bcur);
    k_bscatter2<<<(NE + 4095) / 4096, 1024, 0, stream>>>(row, col, bcur, ebuf);
    k_binfill<<<NB, 256, 0, stream>>>(ebuf, bbase, offs, ends, dinv, csr_src);

    // ---- weights preconvert + encoder (MFMA, chunked out) ----
    k_convW<<<64, 256, 0, stream>>>(Ws, encW, wt, wte);
    k_enc_mfma<<<(NN + 63) / 64, 256, 0, stream>>>(x, wte, encb, hA);

    __half* hcur = hA;
    __half* hnext = hB;
    for (int l = 0; l < NL; ++l) {
        k_gemm_mfma<<<(NN + 63) / 64, 256, 0, stream>>>(hcur, wt + (size_t)l * HID * HID, dinv, hw_);
        k_gather_cp<<<(NN / 16) * NCH, 256, 0, stream>>>(
            offs, ends, csr_src, dinv, hw_, hcur,
            bs + l * HID, gam + l * HID, bet + l * HID, mean + l * HID, var + l * HID,
            hnext, l > 0 ? 1 : 0);
        __half* tmp = hcur; hcur = hnext; hnext = tmp;
    }

    // ---- pool + MLP ----
    k_pool_seg<<<NG, 256, 0, stream>>>(hcur, batch, gfeat);
    k_mlp0<<<NG, 128, 0, stream>>>(gfeat, W0, b0, m0);
    k_mlp1<<<NG, 128, 0, stream>>>(m0, W1, b1, m1);
    k_mlp2<<<NG, 64, 0, stream>>>(m1, W2, b2, out);
}

// Round 14
// 686.683 us; speedup vs baseline: 1.5837x; 1.5837x over previous
//
#include <hip/hip_runtime.h>
#include <hip/hip_fp16.h>

#define NN 100000
#define NE 1600000
#define FIN 64
#define HID 128
#define NL 4
#define NG 512
#define FFN 300
#define BN_EPS 1e-5f
#define LDH 136   // padded LDS stride in halves
#define NB 512    // CSR buckets
#define NPB 196   // nodes per bucket
#define CURPAD 16
#define CH2 64    // features per chunk (2 chunks); chunk slab = NN*64*2B = 12.8 MB

static inline size_t alignup(size_t x) { return (x + 255) & ~(size_t)255; }

struct half8 { __half2 h[4]; };   // 16 B

typedef _Float16 f16;
typedef __attribute__((ext_vector_type(4))) _Float16 f16x4;
typedef __attribute__((ext_vector_type(8))) _Float16 f16x8;
typedef __attribute__((ext_vector_type(4))) float f32x4;

// ======================= CSR build (bucketed, dense writes) =======================
__global__ __launch_bounds__(1024) void k_bcount(const int* __restrict__ col,
                                                 int* __restrict__ bcnt) {
    __shared__ int h[NB];
    int t = threadIdx.x;
    if (t < NB) h[t] = 0;
    __syncthreads();
    for (int e = blockIdx.x * 1024 + t; e < NE; e += 256 * 1024)
        atomicAdd(&h[col[e] / NPB], 1);
    __syncthreads();
    if (t < NB && h[t] > 0) atomicAdd(&bcnt[t], h[t]);
}

__global__ void k_bscan(const int* __restrict__ bcnt, int* __restrict__ bbase,
                        int* __restrict__ bcur) {
    __shared__ int s[NB];
    int t = threadIdx.x;  // NB threads
    int v = bcnt[t];
    s[t] = v;
    __syncthreads();
    for (int off = 1; off < NB; off <<= 1) {
        int u = (t >= off) ? s[t - off] : 0;
        __syncthreads();
        s[t] += u;
        __syncthreads();
    }
    int excl = s[t] - v;
    bbase[t] = excl;
    bcur[t * CURPAD] = excl;
    if (t == NB - 1) bbase[NB] = s[t];
}

__global__ __launch_bounds__(1024) void k_bscatter2(const int* __restrict__ row,
                                                    const int* __restrict__ col,
                                                    int* __restrict__ bcur,
                                                    int* __restrict__ ebuf) {
    __shared__ int hcnt[NB];
    __shared__ int hbase[NB];
    int t = threadIdx.x;
    int e0 = blockIdx.x * 4096;
    if (t < NB) hcnt[t] = 0;
    __syncthreads();
    #pragma unroll
    for (int k = 0; k < 4; ++k) {
        int e = e0 + k * 1024 + t;
        if (e < NE) atomicAdd(&hcnt[col[e] / NPB], 1);
    }
    __syncthreads();
    if (t < NB) {
        int c = hcnt[t];
        hbase[t] = (c > 0) ? atomicAdd(&bcur[t * CURPAD], c) : 0;
    }
    __syncthreads();
    if (t < NB) hcnt[t] = 0;
    __syncthreads();
    #pragma unroll
    for (int k = 0; k < 4; ++k) {
        int e = e0 + k * 1024 + t;
        if (e < NE) {
            int c = col[e];
            int b = c / NPB;
            int loc = atomicAdd(&hcnt[b], 1);
            ebuf[hbase[b] + loc] = row[e] | ((c - b * NPB) << 17);
        }
    }
}

__global__ __launch_bounds__(256) void k_binfill(const int* __restrict__ ebuf,
                                                 const int* __restrict__ bbase,
                                                 int* __restrict__ offs,
                                                 int* __restrict__ ends,
                                                 float* __restrict__ dinv,
                                                 int* __restrict__ csr_src) {
    __shared__ int cnt[NPB];
    __shared__ int scn[256];
    __shared__ int cur[NPB];
    int b = blockIdx.x, t = threadIdx.x;
    int lo = b * NPB;
    int hi = lo + NPB; if (hi > NN) hi = NN;
    int n = hi - lo;
    if (n <= 0) return;
    int s0 = bbase[b], s1 = bbase[b + 1];
    for (int i = t; i < NPB; i += 256) cnt[i] = 0;
    __syncthreads();
    for (int j = s0 + t; j < s1; j += 256)
        atomicAdd(&cnt[((unsigned)ebuf[j]) >> 17], 1);
    __syncthreads();
    int v = (t < n) ? cnt[t] : 0;
    scn[t] = v;
    __syncthreads();
    for (int off = 1; off < 256; off <<= 1) {
        int u = (t >= off) ? scn[t - off] : 0;
        __syncthreads();
        scn[t] += u;
        __syncthreads();
    }
    if (t < n) {
        int g = s0 + scn[t] - v;
        offs[lo + t] = g;
        ends[lo + t] = g + v;
        dinv[lo + t] = rsqrtf((float)(v + 1));
        cur[t] = g;
    }
    __syncthreads();
    for (int j = s0 + t; j < s1; j += 256) {
        int e = ebuf[j];
        int pos = atomicAdd(&cur[((unsigned)e) >> 17], 1);
        csr_src[pos] = e & 0x1FFFF;
    }
}

// ==== W preconvert: wt[l][c][k] = (f16)Ws[l][k][c]; wte[c][k] = (f16)encW[k][c] ====
__global__ void k_convW(const float* __restrict__ Ws, const float* __restrict__ encW,
                        f16* __restrict__ wt, f16* __restrict__ wte) {
    int tid = blockIdx.x * 256 + threadIdx.x;
    for (int i = tid; i < NL * HID * HID; i += 64 * 256) {
        int l = i >> 14, rem = i & 16383;
        int c = rem >> 7, k = rem & 127;
        wt[i] = (f16)Ws[(l << 14) + k * HID + c];
    }
    for (int i = tid; i < HID * FIN; i += 64 * 256) {
        int c = i >> 6, k = i & 63;
        wte[i] = (f16)encW[k * HID + c];
    }
}

// ======== MFMA encoder: chunked out hc[c][row][64] ========
__global__ __launch_bounds__(256) void k_enc_mfma(const float* __restrict__ x,
                                                  const f16* __restrict__ wte,
                                                  const float* __restrict__ b,
                                                  __half* __restrict__ hc) {
    __shared__ f16 sx[64 * 72];
    __shared__ f16 sw[128 * 72];
    int t = threadIdx.x;
    int row0 = blockIdx.x * 64;
    for (int idx = t; idx < 64 * 16; idx += 256) {
        int r = idx >> 4, c4 = (idx & 15) * 4;
        float4 v = {0.0f, 0.0f, 0.0f, 0.0f};
        if (row0 + r < NN) v = *(const float4*)(x + (size_t)(row0 + r) * FIN + c4);
        f16x4 o = {(f16)v.x, (f16)v.y, (f16)v.z, (f16)v.w};
        *(f16x4*)&sx[r * 72 + c4] = o;
    }
    for (int idx = t; idx < 128 * 8; idx += 256) {
        int c = idx >> 3, ch = (idx & 7) * 8;
        *(f16x8*)&sw[c * 72 + ch] = *(const f16x8*)(wte + c * FIN + ch);
    }
    __syncthreads();
    int w = t >> 6, lane = t & 63;
    int lrow = lane & 15, lk = (lane >> 4) * 8;
    f32x4 acc[8];
    #pragma unroll
    for (int ct = 0; ct < 8; ++ct) acc[ct] = (f32x4){0.0f, 0.0f, 0.0f, 0.0f};
    const f16* pa = &sx[(w * 16 + lrow) * 72 + lk];
    #pragma unroll
    for (int ks = 0; ks < 2; ++ks) {
        f16x8 a = *(const f16x8*)(pa + ks * 32);
        #pragma unroll
        for (int ct = 0; ct < 8; ++ct) {
            f16x8 bb = *(const f16x8*)&sw[(ct * 16 + lrow) * 72 + ks * 32 + lk];
            acc[ct] = __builtin_amdgcn_mfma_f32_16x16x32_f16(a, bb, acc[ct], 0, 0, 0);
        }
    }
    float bv[8];
    #pragma unroll
    for (int ct = 0; ct < 8; ++ct) bv[ct] = b[ct * 16 + lrow];
    int rbase = row0 + w * 16 + (lane >> 4) * 4;
    #pragma unroll
    for (int i = 0; i < 4; ++i) {
        int grow = rbase + i;
        if (grow < NN) {
            #pragma unroll
            for (int ct = 0; ct < 8; ++ct)
                hc[((size_t)(ct >> 2) * NN + grow) * CH2 + (ct & 3) * 16 + lrow] =
                    __float2half(acc[ct][i] + bv[ct]);
        }
    }
}

// ==== MFMA layer GEMM: chunked in, chunked out; hw = dinv[row]*(h @ W) ====
__global__ __launch_bounds__(256) void k_gemm_mfma(const __half* __restrict__ hcin,
                                                   const f16* __restrict__ wt,
                                                   const float* __restrict__ dinv,
                                                   __half* __restrict__ hwc) {
    __shared__ f16 sh[64 * LDH];
    __shared__ f16 sw[128 * LDH];
    int t = threadIdx.x;
    int row0 = blockIdx.x * 64;
    // stage 64 rows x 128 features from chunked layout [c][node][64]
    for (int idx = t; idx < 1024; idx += 256) {
        int r = idx >> 4, u = idx & 15;           // u: 16 units of 8 halves
        f16x8 v = {0, 0, 0, 0, 0, 0, 0, 0};
        if (row0 + r < NN)
            v = *(const f16x8*)(hcin + ((size_t)(u >> 3) * NN + row0 + r) * CH2 + (u & 7) * 8);
        *(f16x8*)&sh[r * LDH + u * 8] = v;
    }
    for (int idx = t; idx < 128 * 16; idx += 256) {
        int c = idx >> 4, ch = (idx & 15) * 8;
        *(f16x8*)&sw[c * LDH + ch] = *(const f16x8*)(wt + c * HID + ch);
    }
    __syncthreads();
    int w = t >> 6, lane = t & 63;
    int lrow = lane & 15, lk = (lane >> 4) * 8;
    f32x4 acc[8];
    #pragma unroll
    for (int ct = 0; ct < 8; ++ct) acc[ct] = (f32x4){0.0f, 0.0f, 0.0f, 0.0f};
    const f16* pa = &sh[(w * 16 + lrow) * LDH + lk];
    #pragma unroll
    for (int ks = 0; ks < 4; ++ks) {
        f16x8 a = *(const f16x8*)(pa + ks * 32);
        #pragma unroll
        for (int ct = 0; ct < 8; ++ct) {
            f16x8 b = *(const f16x8*)&sw[(ct * 16 + lrow) * LDH + ks * 32 + lk];
            acc[ct] = __builtin_amdgcn_mfma_f32_16x16x32_f16(a, b, acc[ct], 0, 0, 0);
        }
    }
    int rbase = row0 + w * 16 + (lane >> 4) * 4;
    #pragma unroll
    for (int i = 0; i < 4; ++i) {
        int grow = rbase + i;
        if (grow < NN) {
            float dv = dinv[grow];
            #pragma unroll
            for (int ct = 0; ct < 8; ++ct)
                hwc[((size_t)(ct >> 2) * NN + grow) * CH2 + (ct & 3) * 16 + lrow] =
                    __float2half(dv * acc[ct][i]);
        }
    }
}

// == XCD-pinned 2-chunk gather: chunk = bid&1 (even bids -> XCDs {0,2,4,6}).
//    One wave per node per chunk: 8 edge-slots x 8 lanes x 16B = 128B chunk row.
//    Same load-instruction count as the row-major gather, half the distinct bytes/XCD. ==
__device__ __forceinline__ void add8(float* a, float4 raw) {
    const __half2* p = (const __half2*)&raw;
    #pragma unroll
    for (int q = 0; q < 4; ++q) {
        float2 u = __half22float2(p[q]);
        a[2 * q] += u.x;
        a[2 * q + 1] += u.y;
    }
}

__global__ __launch_bounds__(256) void k_gather_c2(
    const int* __restrict__ offs, const int* __restrict__ ends,
    const int* __restrict__ csr_src,
    const float* __restrict__ dinv,
    const __half* __restrict__ hwc, const __half* __restrict__ hprevc,
    const float* __restrict__ bias, const float* __restrict__ gamma,
    const float* __restrict__ beta, const float* __restrict__ mean,
    const float* __restrict__ var,
    __half* __restrict__ houtc, int with_res) {
    int bid = blockIdx.x;
    int c = bid & 1;                       // chunk, XCD-pinned via round-robin
    int node = ((bid >> 1) * 256 + (int)threadIdx.x) >> 6;
    if (node >= NN) return;
    int lane = threadIdx.x & 63;
    int g = lane >> 3;                     // edge slot (8 per wave)
    int fb = (lane & 7) * 8;               // within-chunk feature base (8 halves = 16B)
    const __half* slab = hwc + (size_t)c * NN * CH2;
    int s = offs[node], e = ends[node];
    float a[8] = {0, 0, 0, 0, 0, 0, 0, 0};
    int j = s + g;
    for (; j + 8 < e; j += 16) {   // 2 loads/slot -> 16 edges, 32 lines in flight
        int s0 = csr_src[j], s1 = csr_src[j + 8];
        float4 r0 = *(const float4*)(slab + (size_t)s0 * CH2 + fb);
        float4 r1 = *(const float4*)(slab + (size_t)s1 * CH2 + fb);
        add8(a, r0);
        add8(a, r1);
    }
    for (; j < e; j += 8) {
        int s0 = csr_src[j];
        float4 r0 = *(const float4*)(slab + (size_t)s0 * CH2 + fb);
        add8(a, r0);
    }
    // combine the 8 edge slots
    #pragma unroll
    for (int q = 0; q < 8; ++q) {
        a[q] += __shfl_xor(a[q], 8);
        a[q] += __shfl_xor(a[q], 16);
        a[q] += __shfl_xor(a[q], 32);
    }
    if (g) return;
    // self-loop (pre-scaled row) then final dinv scale
    float4 sraw = *(const float4*)(slab + (size_t)node * CH2 + fb);
    add8(a, sraw);
    float dc = dinv[node];
    int f0 = c * CH2 + fb;                 // global feature base
    float4 bi0 = *(const float4*)(bias + f0),  bi1 = *(const float4*)(bias + f0 + 4);
    float4 mn0 = *(const float4*)(mean + f0),  mn1 = *(const float4*)(mean + f0 + 4);
    float4 vr0 = *(const float4*)(var + f0),   vr1 = *(const float4*)(var + f0 + 4);
    float4 gm0 = *(const float4*)(gamma + f0), gm1 = *(const float4*)(gamma + f0 + 4);
    float4 bt0 = *(const float4*)(beta + f0),  bt1 = *(const float4*)(beta + f0 + 4);
    float bi[8] = {bi0.x, bi0.y, bi0.z, bi0.w, bi1.x, bi1.y, bi1.z, bi1.w};
    float mn[8] = {mn0.x, mn0.y, mn0.z, mn0.w, mn1.x, mn1.y, mn1.z, mn1.w};
    float vr[8] = {vr0.x, vr0.y, vr0.z, vr0.w, vr1.x, vr1.y, vr1.z, vr1.w};
    float gm[8] = {gm0.x, gm0.y, gm0.z, gm0.w, gm1.x, gm1.y, gm1.z, gm1.w};
    float bt[8] = {bt0.x, bt0.y, bt0.z, bt0.w, bt1.x, bt1.y, bt1.z, bt1.w};
    float o[8];
    #pragma unroll
    for (int q = 0; q < 8; ++q)
        o[q] = fmaxf((dc * a[q] + bi[q] - mn[q]) * rsqrtf(vr[q] + BN_EPS) * gm[q] + bt[q], 0.0f);
    if (with_res) {
        float4 praw = *(const float4*)(hprevc + ((size_t)c * NN + node) * CH2 + fb);
        const __half2* pp = (const __half2*)&praw;
        #pragma unroll
        for (int q = 0; q < 4; ++q) {
            float2 p = __half22float2(pp[q]);
            o[2 * q] += p.x;
            o[2 * q + 1] += p.y;
        }
    }
    half8 ov;
    #pragma unroll
    for (int q = 0; q < 4; ++q)
        ov.h[q] = __floats2half2_rn(o[2 * q], o[2 * q + 1]);
    *(half8*)(houtc + ((size_t)c * NN + node) * CH2 + fb) = ov;
}

// ======================= pool (segmented, chunked input) =======================
__device__ __forceinline__ int lower_bound_dev(const int* __restrict__ a, int n, int v) {
    int lo = 0, hi = n;
    while (lo < hi) {
        int m = (lo + hi) >> 1;
        if (a[m] < v) lo = m + 1; else hi = m;
    }
    return lo;
}

__global__ __launch_bounds__(256) void k_pool_seg(const __half* __restrict__ hc,
                                                  const int* __restrict__ batch,
                                                  float* __restrict__ gfeat) {
    __shared__ int range[2];
    __shared__ float s[256];
    int g = blockIdx.x, t = threadIdx.x;
    if (t == 0) {
        range[0] = lower_bound_dev(batch, NN, g);
        range[1] = lower_bound_dev(batch, NN, g + 1);
    }
    __syncthreads();
    int start = range[0], end = range[1];
    int f = t & 127, half = t >> 7;
    const __half* slab = hc + (size_t)(f >> 6) * NN * CH2;
    int fl = f & 63;
    float acc = 0.0f;
    for (int i = start + half; i < end; i += 2)
        acc += __half2float(slab[(size_t)i * CH2 + fl]);
    s[t] = acc;
    __syncthreads();
    if (t < 128) {
        float sum = s[t] + s[t + 128];
        float cnt = (float)(end - start);
        gfeat[(size_t)g * HID + t] = sum / fmaxf(cnt, 1.0f);
    }
}

// ======================= MLP =======================
__global__ void k_mlp0(const float* __restrict__ gfeat,
                       const float* __restrict__ W, const float* __restrict__ b,
                       float* __restrict__ out) {
    __shared__ float srow[HID];
    int g = blockIdx.x, t = threadIdx.x;  // 128 threads
    if (t < HID) srow[t] = gfeat[(size_t)g * HID + t];
    __syncthreads();
    for (int j = t; j < FFN; j += 128) {
        float acc = b[j];
        for (int k = 0; k < HID; ++k) acc += srow[k] * W[k * FFN + j];
        out[(size_t)g * FFN + j] = fmaxf(acc, 0.0f);
    }
}

__global__ void k_mlp1(const float* __restrict__ in, const float* __restrict__ W,
                       const float* __restrict__ b, float* __restrict__ out) {
    __shared__ float srow[FFN];
    int g = blockIdx.x, t = threadIdx.x;  // 128 threads
    for (int k = t; k < FFN; k += 128) srow[k] = in[(size_t)g * FFN + k];
    __syncthreads();
    for (int j = t; j < FFN; j += 128) {
        float acc = b[j];
        for (int k = 0; k < FFN; ++k) acc += srow[k] * W[k * FFN + j];
        out[(size_t)g * FFN + j] = fmaxf(acc, 0.0f);
    }
}

__global__ void k_mlp2(const float* __restrict__ in, const float* __restrict__ W,
                       const float* __restrict__ b, float* __restrict__ out) {
    int g = blockIdx.x, lane = threadIdx.x;  // 64 threads
    float acc = 0.0f;
    for (int k = lane; k < FFN; k += 64) acc += in[(size_t)g * FFN + k] * W[k];
    for (int off = 32; off > 0; off >>= 1) acc += __shfl_down(acc, off);
    if (lane == 0) out[g] = acc + b[0];
}

extern "C" void kernel_launch(void* const* d_in, const int* in_sizes, int n_in,
                              void* d_out, int out_size, void* d_ws, size_t ws_size,
                              hipStream_t stream) {
    const float* x    = (const float*)d_in[0];
    const int*   ei   = (const int*)d_in[1];    // [2,E]: rows then cols
    const int*   batch= (const int*)d_in[2];
    const float* encW = (const float*)d_in[3];
    const float* encb = (const float*)d_in[4];
    const float* Ws   = (const float*)d_in[5];
    const float* bs   = (const float*)d_in[6];
    const float* gam  = (const float*)d_in[7];
    const float* bet  = (const float*)d_in[8];
    const float* mean = (const float*)d_in[9];
    const float* var  = (const float*)d_in[10];
    const float* W0   = (const float*)d_in[11];
    const float* b0   = (const float*)d_in[12];
    const float* W1   = (const float*)d_in[13];
    const float* b1   = (const float*)d_in[14];
    const float* W2   = (const float*)d_in[15];
    const float* b2   = (const float*)d_in[16];
    float* out = (float*)d_out;

    char* w = (char*)d_ws;
    float*  dinv    = (float*)w;  w += alignup((size_t)NN * 4);
    int*    offs    = (int*)w;    w += alignup((size_t)NN * 4);
    int*    ends    = (int*)w;    w += alignup((size_t)NN * 4);
    int*    csr_src = (int*)w;    w += alignup((size_t)NE * 4);
    int*    bcnt    = (int*)w;    w += alignup((size_t)NB * 4);
    int*    bbase   = (int*)w;    w += alignup((size_t)(NB + 1) * 4);
    int*    bcur    = (int*)w;    w += alignup((size_t)NB * CURPAD * 4);
    int*    ebuf    = (int*)w;    w += alignup((size_t)NE * 4);
    __half* hA      = (__half*)w; w += alignup((size_t)NN * HID * 2);
    __half* hB      = (__half*)w; w += alignup((size_t)NN * HID * 2);
    __half* hw_     = (__half*)w; w += alignup((size_t)NN * HID * 2);
    f16*    wt      = (f16*)w;    w += alignup((size_t)NL * HID * HID * 2);
    f16*    wte     = (f16*)w;    w += alignup((size_t)HID * FIN * 2);
    float*  gfeat   = (float*)w;  w += alignup((size_t)NG * HID * 4);
    float*  m0      = (float*)w;  w += alignup((size_t)NG * FFN * 4);
    float*  m1      = (float*)w;  w += alignup((size_t)NG * FFN * 4);

    const int* row = ei;
    const int* col = ei + NE;

    // ---- CSR build ----
    hipMemsetAsync(bcnt, 0, (size_t)NB * 4, stream);
    k_bcount<<<256, 1024, 0, stream>>>(col, bcnt);
    k_bscan<<<1, NB, 0, stream>>>(bcnt, bbase, bcur);
    k_bscatter2<<<(NE + 4095) / 4096, 1024, 0, stream>>>(row, col, bcur, ebuf);
    k_binfill<<<NB, 256, 0, stream>>>(ebuf, bbase, offs, ends, dinv, csr_src);

    // ---- weights preconvert + encoder (MFMA, chunked out) ----
    k_convW<<<64, 256, 0, stream>>>(Ws, encW, wt, wte);
    k_enc_mfma<<<(NN + 63) / 64, 256, 0, stream>>>(x, wte, encb, hA);

    __half* hcur = hA;
    __half* hnext = hB;
    for (int l = 0; l < NL; ++l) {
        k_gemm_mfma<<<(NN + 63) / 64, 256, 0, stream>>>(hcur, wt + (size_t)l * HID * HID, dinv, hw_);
        k_gather_c2<<<2 * ((NN * 64 + 255) / 256), 256, 0, stream>>>(
            offs, ends, csr_src, dinv, hw_, hcur,
            bs + l * HID, gam + l * HID, bet + l * HID, mean + l * HID, var + l * HID,
            hnext, l > 0 ? 1 : 0);
        __half* tmp = hcur; hcur = hnext; hnext = tmp;
    }

    // ---- pool + MLP ----
    k_pool_seg<<<NG, 256, 0, stream>>>(hcur, batch, gfeat);
    k_mlp0<<<NG, 128, 0, stream>>>(gfeat, W0, b0, m0);
    k_mlp1<<<NG, 128, 0, stream>>>(m0, W1, b1, m1);
    k_mlp2<<<NG, 64, 0, stream>>>(m1, W2, b2, out);
}